// Round 6
// baseline (134.929 us; speedup 1.0000x reference)
//
#include <hip/hip_runtime.h>
#include <math.h>

// FourierBasisTRF: out[b,o,i,w,s] = a[b,s] * ( coefs[o,i,0]*const0
//                    + sum_n basis_n(b,w,s) * norm * coefs[o,i,1+n] )
// T=80, t_emb=w (w in [0,65)), basis interleaved [sin(1t),cos(1t),sin(2t),...],
// t = (2*pi/80) * c[b,s] * (w - b[b,s]).
// Algebra: const0 = norm/sqrt(2) ->
//   out = (a*norm) * ( coefs[oi,0]/sqrt(2) + sum_n coefs[oi,1+n]*bas_n )
//
// R6 design (tail elimination + sequential stream advance):
//  - 520 blocks x 256 thr, each handles 4 consecutive units. Unit =
//    (b, schunk, w) with w fastest: u = (b*4+schunk)*65 + w. All 520 blocks
//    are co-resident (<=3 blocks = 12 waves per CU even at 4 waves/SIMD) ->
//    no partial scheduling round, no idle tail.
//  - Consecutive w per block: each of the block's 64 oi write streams
//    advances +16KB per unit -> sequential HBM pages instead of dead streams.
//  - XCD chunking: 520 = 8*65; XCD x gets g in [65x,65(x+1)) -> exactly b=x.
//  - Unit loop kept rolled (#pragma unroll 1) so VGPR stays ~R5 (~96).
//  - Core per-unit code identical to R5: no LDS, SGPR coefs, f4 stores.

constexpr int S_LEN = 4096;
constexpr int W_LEN = 65;
constexpr int NOI   = 64;   // nOut * nIn
constexpr int NB    = 16;   // 2 * maxN
constexpr int NCOEF = 17;

using f4 = __attribute__((ext_vector_type(4))) float;

__global__ __launch_bounds__(256)
void fourier_basis_trf_kernel(const float* __restrict__ a,
                              const float* __restrict__ b,
                              const float* __restrict__ c,
                              const float* __restrict__ coefs,
                              float* __restrict__ out)
{
    const int tid = threadIdx.x;

    // XCD-chunked block remap (bijective on 520 = 8*65).
    const int hw = blockIdx.x;
    const int g  = (hw & 7) * 65 + (hw >> 3);

    const float K    = 6.283185307179586f / 80.0f;    // 2*pi/T
    const float NORM = 0.15811388300841897f;          // 1/sqrt(40)
    const float RS2  = 0.7071067811865476f;           // 1/sqrt(2)

    #pragma unroll 1
    for (int k = 0; k < 4; ++k) {
        const int u      = g * 4 + k;        // unit id, < 2080
        const int w      = u % W_LEN;
        const int bs     = u / W_LEN;        // = b*4 + schunk
        const int schunk = bs & 3;
        const int bb     = bs >> 2;
        const int s0     = (schunk * 256 + tid) * 4;

        const int abi = bb * S_LEN + s0;
        const f4 av = *reinterpret_cast<const f4*>(a + abi);
        const f4 bv = *reinterpret_cast<const f4*>(b + abi);
        const f4 cv = *reinterpret_cast<const f4*>(c + abi);

        const float tf = (float)w;           // TMIN = 0

        const float a0 = av.x * NORM;
        const float a1 = av.y * NORM;
        const float a2 = av.z * NORM;
        const float a3 = av.w * NORM;

        // Raw sin/cos harmonics (norm folded into a0..a3).
        float bas[NB][4];
        {
            const float xv[4] = { cv.x * (tf - bv.x), cv.y * (tf - bv.y),
                                  cv.z * (tf - bv.z), cv.w * (tf - bv.w) };
            #pragma unroll
            for (int j = 0; j < 4; ++j) {
                float sn, cs;
                sincosf(K * xv[j], &sn, &cs);
                bas[0][j] = sn;
                bas[1][j] = cs;
                float sk = sn, ck = cs;
                #pragma unroll
                for (int kk = 1; kk < 8; ++kk) {
                    const float s2 = fmaf(sk, cs,  ck * sn);
                    const float c2 = fmaf(ck, cs, -sk * sn);
                    bas[2 * kk][j]     = s2;
                    bas[2 * kk + 1][j] = c2;
                    sk = s2;
                    ck = c2;
                }
            }
        }

        // out flat index: (((bb*8+o)*8+i)*65 + w)*4096 + s ; oi = o*8+i
        float* outp = out + ((size_t)bb * NOI * W_LEN + w) * S_LEN + s0;
        constexpr size_t OI_STRIDE = (size_t)W_LEN * S_LEN;  // 266240

        #pragma unroll 2
        for (int oi = 0; oi < NOI; ++oi) {
            const float* cw = coefs + oi * NCOEF;   // wave-uniform -> s_load
            const float d = cw[0] * RS2;
            float x0 = d, x1 = d, x2 = d, x3 = d;
            #pragma unroll
            for (int n = 0; n < NB; ++n) {
                const float cn = cw[1 + n];
                x0 = fmaf(bas[n][0], cn, x0);
                x1 = fmaf(bas[n][1], cn, x1);
                x2 = fmaf(bas[n][2], cn, x2);
                x3 = fmaf(bas[n][3], cn, x3);
            }
            f4 r;
            r.x = x0 * a0;
            r.y = x1 * a1;
            r.z = x2 * a2;
            r.w = x3 * a3;
            *reinterpret_cast<f4*>(outp + (size_t)oi * OI_STRIDE) = r;
        }
    }
}

extern "C" void kernel_launch(void* const* d_in, const int* in_sizes, int n_in,
                              void* d_out, int out_size, void* d_ws, size_t ws_size,
                              hipStream_t stream)
{
    const float* a     = (const float*)d_in[0];
    const float* b     = (const float*)d_in[1];
    const float* c     = (const float*)d_in[2];
    const float* coefs = (const float*)d_in[3];
    float* out = (float*)d_out;

    // 520 blocks = 8 XCD chunks x 65; each block does 4 units of
    // (b, schunk, w). Total units = 8*4*65 = 2080.
    const dim3 grid(520);
    const dim3 block(256);
    fourier_basis_trf_kernel<<<grid, block, 0, stream>>>(a, b, c, coefs, out);
}

// Round 7
// 109.402 us; speedup vs baseline: 1.2333x; 1.2333x over previous
//
#include <hip/hip_runtime.h>
#include <math.h>

// FourierBasisTRF: out[b,o,i,w,s] = a[b,s] * ( coefs[o,i,0]*const0
//                    + sum_n basis_n(b,w,s) * norm * coefs[o,i,1+n] )
// T=80, t_emb=w (w in [0,65)), basis interleaved [sin(1t),cos(1t),sin(2t),...],
// t = (2*pi/80) * c[b,s] * (w - b[b,s]).
// Algebra: const0 = norm/sqrt(2) ->
//   out = (a*norm) * ( coefs[oi,0]/sqrt(2) + sum_n coefs[oi,1+n]*bas_n )
//
// R7 = R5 (best so far, 109us; R6's 520-block variant regressed to 135 --
// high block count is needed for store concurrency) + ONE new lever:
//  - __syncthreads() every 8 oi iterations in the store loop. Keeps the
//    block's 4 waves phase-converged so the 4KB fragment per oi is issued
//    in a tight window -> L2 eviction runs stay address-local instead of
//    interleaving fragments 1.04MB apart from drifted waves.
//  - Everything else identical to R5: 2080 blocks, XCD-chunked swizzle,
//    no LDS, SGPR coefs, f4 stores through L2.

constexpr int S_LEN = 4096;
constexpr int W_LEN = 65;
constexpr int NOI   = 64;   // nOut * nIn
constexpr int NB    = 16;   // 2 * maxN
constexpr int NCOEF = 17;

using f4 = __attribute__((ext_vector_type(4))) float;

__global__ __launch_bounds__(256)
void fourier_basis_trf_kernel(const float* __restrict__ a,
                              const float* __restrict__ b,
                              const float* __restrict__ c,
                              const float* __restrict__ coefs,
                              float* __restrict__ out)
{
    const int tid = threadIdx.x;

    // XCD-chunked swizzle: hw blocks round-robin over 8 XCDs; give XCD x the
    // logical range [x*260, (x+1)*260). 2080 = 8*260 exactly (bijective).
    const int hw  = blockIdx.x;
    const int blk = (hw & 7) * 260 + (hw >> 3);

    const int schunk = blk & 3;          // 4 chunks of 1024 s per (b,w) row
    const int rest   = blk >> 2;         // = bb*W_LEN + w
    const int w      = rest % W_LEN;
    const int bb     = rest / W_LEN;
    const int s0     = (schunk * 256 + tid) * 4;

    const int abi = bb * S_LEN + s0;
    const f4 av = *reinterpret_cast<const f4*>(a + abi);
    const f4 bv = *reinterpret_cast<const f4*>(b + abi);
    const f4 cv = *reinterpret_cast<const f4*>(c + abi);

    const float tf   = (float)w;                      // TMIN = 0
    const float K    = 6.283185307179586f / 80.0f;    // 2*pi/T
    const float NORM = 0.15811388300841897f;          // 1/sqrt(40)
    const float RS2  = 0.7071067811865476f;           // 1/sqrt(2)

    const float a0 = av.x * NORM;
    const float a1 = av.y * NORM;
    const float a2 = av.z * NORM;
    const float a3 = av.w * NORM;

    // Raw sin/cos harmonics (norm folded into a0..a3).
    float bas[NB][4];
    {
        const float xv[4] = { cv.x * (tf - bv.x), cv.y * (tf - bv.y),
                              cv.z * (tf - bv.z), cv.w * (tf - bv.w) };
        #pragma unroll
        for (int j = 0; j < 4; ++j) {
            float sn, cs;
            sincosf(K * xv[j], &sn, &cs);
            bas[0][j] = sn;
            bas[1][j] = cs;
            float sk = sn, ck = cs;
            #pragma unroll
            for (int k = 1; k < 8; ++k) {
                const float s2 = fmaf(sk, cs,  ck * sn);
                const float c2 = fmaf(ck, cs, -sk * sn);
                bas[2 * k][j]     = s2;
                bas[2 * k + 1][j] = c2;
                sk = s2;
                ck = c2;
            }
        }
    }

    // out flat index: (((bb*8+o)*8+i)*65 + w)*4096 + s ; oi = o*8+i
    float* outp = out + ((size_t)bb * NOI * W_LEN + w) * S_LEN + s0;
    constexpr size_t OI_STRIDE = (size_t)W_LEN * S_LEN;  // 266240

    #pragma unroll 2
    for (int oi = 0; oi < NOI; ++oi) {
        if ((oi & 7) == 0) __syncthreads();   // re-converge the block's waves
        const float* cw = coefs + oi * NCOEF; // wave-uniform -> s_load
        const float d = cw[0] * RS2;
        float x0 = d, x1 = d, x2 = d, x3 = d;
        #pragma unroll
        for (int n = 0; n < NB; ++n) {
            const float cn = cw[1 + n];
            x0 = fmaf(bas[n][0], cn, x0);
            x1 = fmaf(bas[n][1], cn, x1);
            x2 = fmaf(bas[n][2], cn, x2);
            x3 = fmaf(bas[n][3], cn, x3);
        }
        f4 r;
        r.x = x0 * a0;
        r.y = x1 * a1;
        r.z = x2 * a2;
        r.w = x3 * a3;
        *reinterpret_cast<f4*>(outp + (size_t)oi * OI_STRIDE) = r;
    }
}

extern "C" void kernel_launch(void* const* d_in, const int* in_sizes, int n_in,
                              void* d_out, int out_size, void* d_ws, size_t ws_size,
                              hipStream_t stream)
{
    const float* a     = (const float*)d_in[0];
    const float* b     = (const float*)d_in[1];
    const float* c     = (const float*)d_in[2];
    const float* coefs = (const float*)d_in[3];
    float* out = (float*)d_out;

    // grid: B * W * (S / (4*256)) = 8 * 65 * 4 = 2080 blocks
    const dim3 grid(8 * W_LEN * 4);
    const dim3 block(256);
    fourier_basis_trf_kernel<<<grid, block, 0, stream>>>(a, b, c, coefs, out);
}